// Round 1
// baseline (1224.662 us; speedup 1.0000x reference)
//
#include <hip/hip_runtime.h>

#define D_FEAT 1443
#define N0     100000
#define KSEL1  50000
#define KSEL2  25000
#define KSEL3  12500
#define SBS    1024   // select kernel block size
#define NBMAX  2048
#define EQCAP  2048
#define WS_ROWS 64

__device__ __forceinline__ unsigned fkey(float f) {
    // monotone map: float order -> unsigned ascending order
    unsigned u = __float_as_uint(f);
    return (u & 0x80000000u) ? ~u : (u | 0x80000000u);
}

// One wave per row: d1[r]=x[r]@w1, d2[r]=x[r]@w2, d3[r]=x[r]@w3.
// Double accumulation to keep our score error well below the np reference's
// own fp32 error (boundary-flip risk reduction). Memory-bound: 577 MB read.
__global__ __launch_bounds__(256) void dots_kernel(
    const float* __restrict__ x,
    const float* __restrict__ w1, const float* __restrict__ w2,
    const float* __restrict__ w3,
    float* __restrict__ d1, float* __restrict__ d2, float* __restrict__ d3)
{
    int wave = threadIdx.x >> 6, lane = threadIdx.x & 63;
    int row = blockIdx.x * 4 + wave;
    if (row >= N0) return;
    const float* xr = x + (long)row * D_FEAT;
    double a1 = 0.0, a2 = 0.0, a3 = 0.0;
    for (int j = lane; j < D_FEAT; j += 64) {
        double xv = (double)xr[j];
        a1 += xv * (double)w1[j];
        a2 += xv * (double)w2[j];
        a3 += xv * (double)w3[j];
    }
    for (int off = 32; off > 0; off >>= 1) {
        a1 += __shfl_down(a1, off);
        a2 += __shfl_down(a2, off);
        a3 += __shfl_down(a3, off);
    }
    if (lane == 0) {
        d1[row] = (float)a1;
        d2[row] = (float)a2;
        d3[row] = (float)a3;
    }
}

// Single-block top-k selection.
//   score_i = tanh(cum_i * d[row_i] / ||w||)
//   select k largest (lowest-position tie-break at the boundary key).
// Outputs exactly k (row, new_cum) pairs (order arbitrary).
__global__ __launch_bounds__(SBS) void select_kernel(
    const float* __restrict__ dvec,       // dots indexed by ORIGINAL row
    const float* __restrict__ w,          // for ||w||
    const int*   __restrict__ idxIn,      // nullptr on round 1 (identity)
    const float* __restrict__ cumIn,      // nullptr on round 1 (ones)
    int n, int k,
    unsigned* __restrict__ keys, float* __restrict__ svals,   // scratch len n
    int* __restrict__ idxOut, float* __restrict__ cumOut,     // len k
    float* __restrict__ zeroPtr, int zeroN)                   // optional d_out zeroing
{
    __shared__ unsigned hist[4][NBMAX];       // 4 privatized copies (contention)
    __shared__ unsigned sufA[NBMAX], sufB[NBMAX];
    __shared__ int eqbuf[EQCAP];
    __shared__ double redbuf[SBS / 64];
    __shared__ float sInvNorm;
    __shared__ unsigned sBin, sKRem;
    __shared__ int sEqCount, sCutoff, sOutCount, sEqTaken;

    int tid = threadIdx.x;
    int copy = tid >> 8;   // 256 threads per histogram copy

    // zero the final output buffer if requested (round 3); harness poisons it
    for (int i = tid; i < zeroN; i += SBS) zeroPtr[i] = 0.0f;

    // ||w||  (uniform scale -> cannot change ranking, only tiny value shift)
    double nl = 0.0;
    for (int j = tid; j < D_FEAT; j += SBS) { double wv = (double)w[j]; nl += wv * wv; }
    for (int off = 32; off > 0; off >>= 1) nl += __shfl_down(nl, off);
    if ((tid & 63) == 0) redbuf[tid >> 6] = nl;
    __syncthreads();
    if (tid == 0) {
        double t = 0.0;
        for (int i = 0; i < SBS / 64; i++) t += redbuf[i];
        sInvNorm = (float)(1.0 / sqrt(t));
        sEqCount = 0; sOutCount = 0; sEqTaken = 0;
    }
    __syncthreads();
    float invNorm = sInvNorm;

    // scores + order-preserving keys
    for (int i = tid; i < n; i += SBS) {
        int   row = idxIn ? idxIn[i] : i;
        float c   = idxIn ? cumIn[i] : 1.0f;
        float s   = tanhf(c * dvec[row] * invNorm);
        svals[i] = s;
        keys[i]  = fkey(s);
    }
    __syncthreads();

    // 3-level radix select for the k-th largest key
    unsigned prefix = 0, pmask = 0;
    int kRem = k;
    const int shifts[3] = {21, 10, 0};
    const int nbs[3]    = {2048, 2048, 1024};
    for (int lev = 0; lev < 3; lev++) {
        int sh = shifts[lev], nb = nbs[lev];
        for (int b = tid; b < 4 * NBMAX; b += SBS) ((unsigned*)hist)[b] = 0u;
        __syncthreads();
        for (int i = tid; i < n; i += SBS) {
            unsigned key = keys[i];
            if ((key & pmask) == prefix)
                atomicAdd(&hist[copy][(key >> sh) & (unsigned)(nb - 1)], 1u);
        }
        __syncthreads();
        // inclusive suffix sums over nb bins (double-buffered Hillis-Steele)
        for (int b = tid; b < nb; b += SBS)
            sufA[b] = hist[0][b] + hist[1][b] + hist[2][b] + hist[3][b];
        __syncthreads();
        unsigned* src = sufA; unsigned* dst = sufB;
        for (int off = 1; off < nb; off <<= 1) {
            for (int b = tid; b < nb; b += SBS)
                dst[b] = src[b] + ((b + off < nb) ? src[b + off] : 0u);
            __syncthreads();
            unsigned* t2 = src; src = dst; dst = t2;
        }
        // unique bin b with suffix[b] >= kRem > suffix[b+1]
        for (int b = tid; b < nb; b += SBS) {
            unsigned sb = src[b];
            unsigned sn = (b + 1 < nb) ? src[b + 1] : 0u;
            if (sb >= (unsigned)kRem && sn < (unsigned)kRem) {
                sBin = (unsigned)b;
                sKRem = (unsigned)kRem - sn;
            }
        }
        __syncthreads();
        prefix |= sBin << sh;
        pmask  |= (unsigned)(nb - 1) << sh;
        kRem    = (int)sKRem;
        __syncthreads();
    }
    unsigned thrKey = prefix;   // exact key of k-th largest
    int need = kRem;            // how many elements equal to thrKey to take

    // boundary ties: take the `need` lowest positions among key == thrKey
    for (int i = tid; i < n; i += SBS) {
        if (keys[i] == thrKey) {
            int p = atomicAdd(&sEqCount, 1);
            if (p < EQCAP) eqbuf[p] = i;
        }
    }
    __syncthreads();
    if (tid == 0) {
        int m = sEqCount < EQCAP ? sEqCount : EQCAP;
        int cutoff = 0x7FFFFFFF;
        if (sEqCount <= EQCAP) {
            for (int t = 0; t < need; t++) {      // need-th smallest position
                int mi = 0x7FFFFFFF, arg = -1;
                for (int e = 0; e < m; e++)
                    if (eqbuf[e] < mi) { mi = eqbuf[e]; arg = e; }
                cutoff = mi;
                if (arg >= 0) eqbuf[arg] = 0x7FFFFFFF;
            }
        }
        sCutoff = cutoff;
    }
    __syncthreads();
    int cutoff = sCutoff;

    // compact: exactly k survivors (quota guarantees exact count)
    for (int i = tid; i < n; i += SBS) {
        unsigned key = keys[i];
        bool sel = (key > thrKey);
        if (!sel && key == thrKey && i <= cutoff) {
            int q = atomicAdd(&sEqTaken, 1);
            sel = (q < need);
        }
        if (sel) {
            int pos = atomicAdd(&sOutCount, 1);
            int   row = idxIn ? idxIn[i] : i;
            float c   = idxIn ? cumIn[i] : 1.0f;
            idxOut[pos] = row;
            cumOut[pos] = c * svals[i];
        }
    }
}

// out[c] = (1/12500) * sum_r cum3[r] * x[idx3[r]][c]   (atomic partials)
__global__ __launch_bounds__(256) void wsum_kernel(
    const float* __restrict__ x, const int* __restrict__ idx3,
    const float* __restrict__ cum3, float* __restrict__ out)
{
    int col = blockIdx.x * 256 + threadIdx.x;
    int r0 = blockIdx.y * WS_ROWS;
    int r1 = r0 + WS_ROWS; if (r1 > KSEL3) r1 = KSEL3;
    float acc = 0.0f;
    for (int r = r0; r < r1; r++) {
        int   row = idx3[r];
        float wgt = cum3[r];
        if (col < D_FEAT) acc += wgt * x[(long)row * D_FEAT + col];
    }
    if (col < D_FEAT) atomicAdd(&out[col], acc * (1.0f / (float)KSEL3));
}

extern "C" void kernel_launch(void* const* d_in, const int* in_sizes, int n_in,
                              void* d_out, int out_size, void* d_ws, size_t ws_size,
                              hipStream_t stream) {
    const float* x  = (const float*)d_in[0];
    const float* w1 = (const float*)d_in[3];
    const float* w2 = (const float*)d_in[4];
    const float* w3 = (const float*)d_in[5];
    float* out = (float*)d_out;

    float* ws = (float*)d_ws;
    float*    d1   = ws;                          // 100000
    float*    d2   = ws + 100000;                 // 100000
    float*    d3   = ws + 200000;                 // 100000
    unsigned* keys = (unsigned*)(ws + 300000);    // 100000
    float*    sv   = ws + 400000;                 // 100000
    int*      idx1 = (int*)(ws + 500000);         // 50000
    float*    cum1 = ws + 550000;                 // 50000
    int*      idx2 = (int*)(ws + 600000);         // 25000
    float*    cum2 = ws + 625000;                 // 25000
    int*      idx3 = (int*)(ws + 650000);         // 12500
    float*    cum3 = ws + 662500;                 // 12500

    dots_kernel<<<dim3(N0 / 4), dim3(256), 0, stream>>>(x, w1, w2, w3, d1, d2, d3);

    select_kernel<<<1, SBS, 0, stream>>>(d1, w1, nullptr, nullptr, N0, KSEL1,
                                         keys, sv, idx1, cum1, nullptr, 0);
    select_kernel<<<1, SBS, 0, stream>>>(d2, w2, idx1, cum1, KSEL1, KSEL2,
                                         keys, sv, idx2, cum2, nullptr, 0);
    select_kernel<<<1, SBS, 0, stream>>>(d3, w3, idx2, cum2, KSEL2, KSEL3,
                                         keys, sv, idx3, cum3, out, out_size);

    wsum_kernel<<<dim3((D_FEAT + 255) / 256, (KSEL3 + WS_ROWS - 1) / WS_ROWS),
                  dim3(256), 0, stream>>>(x, idx3, cum3, out);
}

// Round 2
// 1019.799 us; speedup vs baseline: 1.2009x; 1.2009x over previous
//
#include <hip/hip_runtime.h>
#include <math.h>

#define D_FEAT 1443
#define N0     100000
#define K1SEL  50000
#define K2SEL  25000
#define K3SEL  12500
#define NB     65536
#define EQCAP  4096

// state layout (ints): [0]=prefix1 [1]=thrKey [2]=kRem/need [3]=cntEq
// [4]=eqCount [5]=outCount  [8..10]=invNorm(w1..w3) as float  [16..16+EQCAP)=eqbuf

__device__ __forceinline__ unsigned fkey(float f) {
    unsigned u = __float_as_uint(f);
    return (u & 0x80000000u) ? ~u : (u | 0x80000000u);
}

// zero histograms + d_out; compute 1/||w|| for all three w's (block 0)
__global__ __launch_bounds__(256) void init_kernel(
    const float* __restrict__ w1, const float* __restrict__ w2,
    const float* __restrict__ w3,
    unsigned* __restrict__ hist1, unsigned* __restrict__ hist2,
    int* __restrict__ st, float* __restrict__ out, int outN)
{
    int gid = blockIdx.x * 256 + threadIdx.x;
    int gsz = gridDim.x * 256;
    for (int i = gid; i < NB; i += gsz) { hist1[i] = 0u; hist2[i] = 0u; }
    for (int i = gid; i < outN; i += gsz) out[i] = 0.0f;
    if (blockIdx.x == 0) {
        __shared__ double red[4];
        const float* ws_[3] = { w1, w2, w3 };
        for (int r = 0; r < 3; r++) {
            double nl = 0.0;
            for (int j = threadIdx.x; j < D_FEAT; j += 256) {
                double wv = (double)ws_[r][j]; nl += wv * wv;
            }
            for (int off = 32; off > 0; off >>= 1) nl += __shfl_down(nl, off);
            if ((threadIdx.x & 63) == 0) red[threadIdx.x >> 6] = nl;
            __syncthreads();
            if (threadIdx.x == 0)
                ((float*)st)[8 + r] = (float)(1.0 / sqrt(red[0] + red[1] + red[2] + red[3]));
            __syncthreads();
        }
        if (threadIdx.x < 8) st[threadIdx.x] = 0;
    }
}

// one wave per row: d2=x@w2, d3=x@w3; round-1 score/key/hist fused (d1 never stored)
__global__ __launch_bounds__(256) void dots_kernel(
    const float* __restrict__ x,
    const float* __restrict__ w1, const float* __restrict__ w2,
    const float* __restrict__ w3,
    float* __restrict__ d2, float* __restrict__ d3,
    unsigned* __restrict__ keys, float* __restrict__ sv,
    unsigned* __restrict__ hist1, const int* __restrict__ st)
{
    int wave = threadIdx.x >> 6, lane = threadIdx.x & 63;
    int row = blockIdx.x * 4 + wave;
    if (row >= N0) return;
    const float* xr = x + (long)row * D_FEAT;
    double a1 = 0.0, a2 = 0.0, a3 = 0.0;
    for (int j = lane; j < D_FEAT; j += 64) {
        double xv = (double)xr[j];
        a1 += xv * (double)w1[j];
        a2 += xv * (double)w2[j];
        a3 += xv * (double)w3[j];
    }
    for (int off = 32; off > 0; off >>= 1) {
        a1 += __shfl_down(a1, off);
        a2 += __shfl_down(a2, off);
        a3 += __shfl_down(a3, off);
    }
    if (lane == 0) {
        d2[row] = (float)a2;
        d3[row] = (float)a3;
        float invN = ((const float*)st)[8];
        float s = tanhf((float)a1 * invN);
        sv[row] = s;
        unsigned key = fkey(s);
        keys[row] = key;
        atomicAdd(&hist1[key >> 16], 1u);
    }
}

// rounds 2/3: score from cum*d, build level-1 histogram
__global__ __launch_bounds__(256) void score_kernel(
    const float* __restrict__ dvec, const int* __restrict__ idxIn,
    const float* __restrict__ cumIn, int n, int wIdx,
    unsigned* __restrict__ keys, float* __restrict__ sv,
    unsigned* __restrict__ hist1, const int* __restrict__ st)
{
    int gid = blockIdx.x * 256 + threadIdx.x;
    if (gid >= n) return;
    float invN = ((const float*)st)[8 + wIdx];
    int row = idxIn[gid];
    float c = cumIn[gid];
    float s = tanhf(c * dvec[row] * invN);
    sv[gid] = s;
    unsigned key = fkey(s);
    keys[gid] = key;
    atomicAdd(&hist1[key >> 16], 1u);
}

// level-2 histogram: low 16 bits of keys whose high 16 bits match prefix1
__global__ __launch_bounds__(256) void hist2_kernel(
    const unsigned* __restrict__ keys, int n,
    unsigned* __restrict__ hist2, const int* __restrict__ st)
{
    int gid = blockIdx.x * 256 + threadIdx.x;
    if (gid >= n) return;
    unsigned p1 = (unsigned)st[0];
    unsigned k = keys[gid];
    if ((k >> 16) == p1) atomicAdd(&hist2[k & 0xFFFFu], 1u);
}

// single block: find bin b with suffix(b) >= kRem > suffix(b+1) over 65536 bins
__global__ __launch_bounds__(1024) void pick_kernel(
    const unsigned* __restrict__ hist, int* __restrict__ st, int level, int k0)
{
    __shared__ unsigned csuf[1024];
    int tid = threadIdx.x;
    unsigned kRem = (level == 1) ? (unsigned)k0 : (unsigned)st[2];
    int base = tid * 64;
    unsigned s = 0;
    for (int b = 0; b < 64; b++) s += hist[base + b];
    csuf[tid] = s;
    __syncthreads();
    for (int off = 1; off < 1024; off <<= 1) {
        unsigned v = csuf[tid] + ((tid + off < 1024) ? csuf[tid + off] : 0u);
        __syncthreads();
        csuf[tid] = v;
        __syncthreads();
    }
    unsigned suf = csuf[tid];
    unsigned sufNext = (tid < 1023) ? csuf[tid + 1] : 0u;
    if (suf >= kRem && sufNext < kRem) {
        unsigned acc = sufNext, hsel = 0; int sel = base;
        for (int b = base + 63; b >= base; b--) {
            unsigned h = hist[b];
            acc += h;
            if (acc >= kRem) { sel = b; hsel = h; break; }
        }
        unsigned needNext = kRem - (acc - hsel);
        if (level == 1) {
            st[0] = sel;
            st[2] = (int)needNext;
        } else {
            st[1] = (int)(((unsigned)st[0] << 16) | (unsigned)sel);
            st[2] = (int)needNext;
            st[3] = (int)hsel;
            st[4] = 0;
            st[5] = 0;
        }
    }
}

// compact survivors (key > thr); record boundary ties; zero hists for next round
__global__ __launch_bounds__(256) void compact_kernel(
    const unsigned* __restrict__ keys, const float* __restrict__ sv,
    const int* __restrict__ idxIn, const float* __restrict__ cumIn,
    int n, int* __restrict__ idxOut, float* __restrict__ cumOut,
    int* __restrict__ st,
    unsigned* __restrict__ hist1, unsigned* __restrict__ hist2, int doZero)
{
    int gid = blockIdx.x * 256 + threadIdx.x;
    int gsz = gridDim.x * 256;
    if (doZero) {
        for (int i = gid; i < NB; i += gsz) { hist1[i] = 0u; hist2[i] = 0u; }
    }
    if (gid >= n) return;
    unsigned thr = (unsigned)st[1];
    unsigned key = keys[gid];
    if (key > thr) {
        int pos = atomicAdd(&st[5], 1);
        idxOut[pos] = idxIn ? idxIn[gid] : gid;
        cumOut[pos] = (idxIn ? cumIn[gid] : 1.0f) * sv[gid];
    } else if (key == thr) {
        int e = atomicAdd(&st[4], 1);
        if (e < EQCAP) st[16 + e] = gid;
    }
}

// boundary ties: take `need` lowest positions among key == thr (cnt ~ 1 in practice)
__global__ __launch_bounds__(256) void tie_kernel(
    const float* __restrict__ sv, const int* __restrict__ idxIn,
    const float* __restrict__ cumIn, int k,
    int* __restrict__ idxOut, float* __restrict__ cumOut, int* __restrict__ st)
{
    int cnt = st[4]; if (cnt > EQCAP) cnt = EQCAP;
    int need = st[2];
    int base = k - need;
    for (int e = threadIdx.x; e < cnt; e += 256) {
        int pos = st[16 + e];
        int rank = 0;
        for (int e2 = 0; e2 < cnt; e2++) rank += (st[16 + e2] < pos) ? 1 : 0;
        if (rank < need) {
            idxOut[base + rank] = idxIn ? idxIn[pos] : pos;
            cumOut[base + rank] = (idxIn ? cumIn[pos] : 1.0f) * sv[pos];
        }
    }
}

#define WS_ROWS 64
// out[c] += (1/K3SEL) * sum_r cum3[r] * x[idx3[r]][c]
__global__ __launch_bounds__(256) void wsum_kernel(
    const float* __restrict__ x, const int* __restrict__ idx3,
    const float* __restrict__ cum3, float* __restrict__ out)
{
    int col = blockIdx.x * 256 + threadIdx.x;
    int r0 = blockIdx.y * WS_ROWS;
    int r1 = r0 + WS_ROWS; if (r1 > K3SEL) r1 = K3SEL;
    float acc = 0.0f;
    for (int r = r0; r < r1; r++) {
        int row = idx3[r];
        float wgt = cum3[r];
        if (col < D_FEAT) acc += wgt * x[(long)row * D_FEAT + col];
    }
    if (col < D_FEAT) atomicAdd(&out[col], acc * (1.0f / (float)K3SEL));
}

extern "C" void kernel_launch(void* const* d_in, const int* in_sizes, int n_in,
                              void* d_out, int out_size, void* d_ws, size_t ws_size,
                              hipStream_t stream) {
    const float* x  = (const float*)d_in[0];
    const float* w1 = (const float*)d_in[3];
    const float* w2 = (const float*)d_in[4];
    const float* w3 = (const float*)d_in[5];
    float* out = (float*)d_out;

    float* ws = (float*)d_ws;
    float*    d2    = ws;                         // 100000
    float*    d3    = ws + 100000;                // 100000
    unsigned* keys  = (unsigned*)(ws + 200000);   // 100000
    float*    sv    = ws + 300000;                // 100000
    int*      idx1  = (int*)(ws + 400000);        // 50000
    float*    cum1  = ws + 450000;                // 50000
    int*      idx2  = (int*)(ws + 500000);        // 25000
    float*    cum2  = ws + 525000;                // 25000
    int*      idx3  = (int*)(ws + 550000);        // 12500
    float*    cum3  = ws + 562500;                // 12500
    unsigned* hist1 = (unsigned*)(ws + 575000);   // 65536
    unsigned* hist2 = (unsigned*)(ws + 575000 + NB); // 65536
    int*      st    = (int*)(ws + 575000 + 2 * NB);  // 16 + EQCAP

    init_kernel<<<dim3(256), dim3(256), 0, stream>>>(w1, w2, w3, hist1, hist2, st, out, out_size);

    dots_kernel<<<dim3(N0 / 4), dim3(256), 0, stream>>>(x, w1, w2, w3, d2, d3,
                                                        keys, sv, hist1, st);

    // ---- round 1: n=100000 -> k=50000
    pick_kernel<<<1, 1024, 0, stream>>>(hist1, st, 1, K1SEL);
    hist2_kernel<<<dim3((N0 + 255) / 256), dim3(256), 0, stream>>>(keys, N0, hist2, st);
    pick_kernel<<<1, 1024, 0, stream>>>(hist2, st, 2, 0);
    compact_kernel<<<dim3((N0 + 255) / 256), dim3(256), 0, stream>>>(
        keys, sv, nullptr, nullptr, N0, idx1, cum1, st, hist1, hist2, 1);
    tie_kernel<<<1, 256, 0, stream>>>(sv, nullptr, nullptr, K1SEL, idx1, cum1, st);

    // ---- round 2: n=50000 -> k=25000
    score_kernel<<<dim3((K1SEL + 255) / 256), dim3(256), 0, stream>>>(
        d2, idx1, cum1, K1SEL, 1, keys, sv, hist1, st);
    pick_kernel<<<1, 1024, 0, stream>>>(hist1, st, 1, K2SEL);
    hist2_kernel<<<dim3((K1SEL + 255) / 256), dim3(256), 0, stream>>>(keys, K1SEL, hist2, st);
    pick_kernel<<<1, 1024, 0, stream>>>(hist2, st, 2, 0);
    compact_kernel<<<dim3((K1SEL + 255) / 256), dim3(256), 0, stream>>>(
        keys, sv, idx1, cum1, K1SEL, idx2, cum2, st, hist1, hist2, 1);
    tie_kernel<<<1, 256, 0, stream>>>(sv, idx1, cum1, K2SEL, idx2, cum2, st);

    // ---- round 3: n=25000 -> k=12500
    score_kernel<<<dim3((K2SEL + 255) / 256), dim3(256), 0, stream>>>(
        d3, idx2, cum2, K2SEL, 2, keys, sv, hist1, st);
    pick_kernel<<<1, 1024, 0, stream>>>(hist1, st, 1, K3SEL);
    hist2_kernel<<<dim3((K2SEL + 255) / 256), dim3(256), 0, stream>>>(keys, K2SEL, hist2, st);
    pick_kernel<<<1, 1024, 0, stream>>>(hist2, st, 2, 0);
    compact_kernel<<<dim3((K2SEL + 255) / 256), dim3(256), 0, stream>>>(
        keys, sv, idx2, cum2, K2SEL, idx3, cum3, st, hist1, hist2, 0);
    tie_kernel<<<1, 256, 0, stream>>>(sv, idx2, cum2, K3SEL, idx3, cum3, st);

    // ---- final mean over 12500 weighted rows
    wsum_kernel<<<dim3((D_FEAT + 255) / 256, (K3SEL + WS_ROWS - 1) / WS_ROWS),
                  dim3(256), 0, stream>>>(x, idx3, cum3, out);
}